// Round 8
// baseline (842.687 us; speedup 1.0000x reference)
//
#include <hip/hip_runtime.h>
#include <hip/hip_fp16.h>
#include <cstdint>
#include <cstddef>

// ---------------------------------------------------------------------------
// GCNClassifier: 3x (GCNConv + tanh) + linear head, N=100k nodes, E=3.2M edges
// Round 8: plane-split fp16 gather buffers. Round-7 pull_agg_h<128> fetched
// 557 MB vs 819 MB logical (34% hit): per-XCD L2 (4 MB) vs 25.6 MB random
// working set -> capacity-limited. Hs is now stored as 32-column fp16 planes
// (6.4 MB each); one pull dispatch per plane shrinks the per-dispatch random
// working set to ~L2 size. Row-per-plane = 64 B = one cache line.
//   Hs[v]  = fp16( (X@W)[v] * dinv[v] )               (gemm epilogue, planed)
//   out[v] = tanh( dinv[v]*(Hs[v] + sum_{u->v} Hs[u]) + b )   (pull, fused)
// CSR built atomic-free (bucketed counting sort, round 7). edge_index int32.
// ---------------------------------------------------------------------------

#define EPB 16384        // edges per hist/scatter chunk
#define BSHIFT 8         // bucket = dst >> 8 (256 dst nodes per bucket)
#define NBUC_MAX 512     // 100000>>8 = 390 max bucket id
#define BCAP 12800       // bucket_build LDS edge capacity (avg 8192, 50+ sigma)

// --- generic two-level exclusive scan ---
__global__ __launch_bounds__(256) void scan_block(const int* __restrict__ src, int n,
                                                  int* __restrict__ incl,
                                                  int* __restrict__ bsum) {
    int tid = threadIdx.x;
    int v = blockIdx.x * 256 + tid;
    int val = (v < n) ? src[v] : 0;
    int lane = tid & 63, w = tid >> 6;
#pragma unroll
    for (int off = 1; off < 64; off <<= 1) {
        int t = __shfl_up(val, off, 64);
        if (lane >= off) val += t;
    }
    __shared__ int wsum[4];
    if (lane == 63) wsum[w] = val;
    __syncthreads();
#pragma unroll
    for (int i = 0; i < 4; ++i)
        if (i < w) val += wsum[i];
    if (v < n) incl[v] = val;
    if (tid == 255) bsum[blockIdx.x] = val;
}

__global__ __launch_bounds__(512) void scan_sums(int* __restrict__ bsum, int nb) {
    int tid = threadIdx.x;              // nb <= 512
    int val = (tid < nb) ? bsum[tid] : 0;
    int lane = tid & 63, w = tid >> 6;
#pragma unroll
    for (int off = 1; off < 64; off <<= 1) {
        int t = __shfl_up(val, off, 64);
        if (lane >= off) val += t;
    }
    __shared__ int wsum[8];
    if (lane == 63) wsum[w] = val;
    __syncthreads();
#pragma unroll
    for (int i = 0; i < 8; ++i)
        if (i < w) val += wsum[i];
    if (tid < nb) bsum[tid] = val;
}

__global__ __launch_bounds__(256) void finalize_scan(
    const int* __restrict__ incl, const int* __restrict__ bsum,
    const int* __restrict__ src, int n, int* __restrict__ excl) {
    int v = blockIdx.x * 256 + threadIdx.x;
    if (v >= n) return;
    int boff = (blockIdx.x == 0) ? 0 : bsum[blockIdx.x - 1];
    excl[v] = boff + incl[v] - src[v];
}

// Pass A: per-chunk histogram over dst buckets (LDS atomics only).
__global__ __launch_bounds__(256) void hist_bucket(
    const int* __restrict__ ei, int E, int nbuc, int nch,
    int* __restrict__ histG) {
    __shared__ int h[NBUC_MAX];
    const int k = blockIdx.x;
    for (int b = threadIdx.x; b < NBUC_MAX; b += 256) h[b] = 0;
    __syncthreads();
    const int base = k * EPB, end = min(E, base + EPB);
    for (int i = base + threadIdx.x; i < end; i += 256)
        atomicAdd(&h[ei[(size_t)E + i] >> BSHIFT], 1);
    __syncthreads();
    for (int b = threadIdx.x; b < nbuc; b += 256)
        histG[(size_t)b * nch + k] = h[b];
}

// Pass C: scatter (src,dst) pairs into per-(bucket,chunk) contiguous regions.
__global__ __launch_bounds__(256) void bucket_scatter(
    const int* __restrict__ ei, int E, int nbuc, int nch,
    const int* __restrict__ offs, uint2* __restrict__ ebuf) {
    __shared__ int cur[NBUC_MAX];
    const int k = blockIdx.x;
    for (int b = threadIdx.x; b < nbuc; b += 256)
        cur[b] = offs[(size_t)b * nch + k];
    __syncthreads();
    const int base = k * EPB, end = min(E, base + EPB);
    for (int i = base + threadIdx.x; i < end; i += 256) {
        int s = ei[i];
        int d = ei[(size_t)E + i];
        int pos = atomicAdd(&cur[d >> BSHIFT], 1);
        ebuf[pos] = make_uint2((unsigned)s, (unsigned)d);
    }
}

// Pass D: one block per bucket -> exact CSR slice + deg/row_start/dinv.
__global__ __launch_bounds__(256) void bucket_build(
    const uint2* __restrict__ ebuf, const int* __restrict__ offs,
    int E, int nbuc, int nch, int n,
    int* __restrict__ col, int* __restrict__ deg,
    int* __restrict__ row_start, float* __restrict__ dinv) {
    const int b = blockIdx.x;
    const int tid = threadIdx.x;
    const int estart = offs[(size_t)b * nch];
    const int eend = (b + 1 < nbuc) ? offs[(size_t)(b + 1) * nch] : E;
    const int cnt = eend - estart;

    __shared__ int degl[256];
    __shared__ int curl[256];
    __shared__ int wsum[4];
    __shared__ int colstage[BCAP];

    degl[tid] = 0;
    __syncthreads();
    for (int i = tid; i < cnt; i += 256)
        atomicAdd(&degl[ebuf[estart + i].y & 255], 1);
    __syncthreads();
    int myDeg = degl[tid];
    int val = myDeg;
    int lane = tid & 63, w = tid >> 6;
#pragma unroll
    for (int off = 1; off < 64; off <<= 1) {
        int t = __shfl_up(val, off, 64);
        if (lane >= off) val += t;
    }
    if (lane == 63) wsum[w] = val;
    __syncthreads();
#pragma unroll
    for (int i = 0; i < 4; ++i)
        if (i < w) val += wsum[i];
    int excl = val - myDeg;
    curl[tid] = excl;
    int v = (b << BSHIFT) + tid;
    if (v < n) {
        deg[v] = myDeg;
        row_start[v] = estart + excl;
        dinv[v] = rsqrtf((float)(myDeg + 1));   // +1 self loop
    }
    __syncthreads();
    if (cnt <= BCAP) {
        for (int i = tid; i < cnt; i += 256) {
            uint2 e = ebuf[estart + i];
            int pos = atomicAdd(&curl[e.y & 255], 1);
            colstage[pos] = (int)e.x;
        }
        __syncthreads();
        for (int i = tid; i < cnt; i += 256)
            col[estart + i] = colstage[i];
    } else {  // safety fallback
        for (int i = tid; i < cnt; i += 256) {
            uint2 e = ebuf[estart + i];
            int pos = atomicAdd(&curl[e.y & 255], 1);
            col[estart + pos] = (int)e.x;
        }
    }
}

__device__ inline unsigned int pack2h(float a, float b) {
    __half ha = __float2half_rn(a), hb = __float2half_rn(b);
    unsigned short ua = *(unsigned short*)&ha, ub = *(unsigned short*)&hb;
    return (unsigned int)ua | ((unsigned int)ub << 16);
}

// Register-tiled GEMM: Hs = fp16( (X@W) * dinv[row] ), written in PLANEW-col
// planes (plane p at Hs + p*n*PLANEW, row stride PLANEW).
template <int FIN, int FOUT, int TM, int PLANEW>
__global__ __launch_bounds__(256) void gemm_tile_p(
    const float* __restrict__ X, const float* __restrict__ W,
    const float* __restrict__ dinv, __half* __restrict__ Hs, int n) {
    constexpr int CT = FOUT / 4;
    constexpr int RG = 256 / CT;
    static_assert(TM == RG * 4, "tile mismatch");
    constexpr int LROW = FIN + 4;
    __shared__ float xs[TM][LROW];

    const int node0 = blockIdx.x * TM;
    const int tid = threadIdx.x;

    constexpr int C4 = FIN / 4;
    for (int i = tid; i < TM * C4; i += 256) {
        int r = i / C4, c = i % C4;
        float4 v = make_float4(0.f, 0.f, 0.f, 0.f);
        if (node0 + r < n) v = *(const float4*)(X + (size_t)(node0 + r) * FIN + c * 4);
        *(float4*)&xs[r][c * 4] = v;
    }
    __syncthreads();

    const int col = (tid % CT) * 4;
    const int r0 = (tid / CT) * 4;

    float acc[4][4];
#pragma unroll
    for (int i = 0; i < 4; ++i)
#pragma unroll
        for (int j = 0; j < 4; ++j) acc[i][j] = 0.f;

#pragma unroll 8
    for (int k = 0; k < FIN; ++k) {
        float4 b = *(const float4*)(W + (size_t)k * FOUT + col);
        float a0 = xs[r0 + 0][k];
        float a1 = xs[r0 + 1][k];
        float a2 = xs[r0 + 2][k];
        float a3 = xs[r0 + 3][k];
        acc[0][0] = fmaf(a0, b.x, acc[0][0]); acc[0][1] = fmaf(a0, b.y, acc[0][1]);
        acc[0][2] = fmaf(a0, b.z, acc[0][2]); acc[0][3] = fmaf(a0, b.w, acc[0][3]);
        acc[1][0] = fmaf(a1, b.x, acc[1][0]); acc[1][1] = fmaf(a1, b.y, acc[1][1]);
        acc[1][2] = fmaf(a1, b.z, acc[1][2]); acc[1][3] = fmaf(a1, b.w, acc[1][3]);
        acc[2][0] = fmaf(a2, b.x, acc[2][0]); acc[2][1] = fmaf(a2, b.y, acc[2][1]);
        acc[2][2] = fmaf(a2, b.z, acc[2][2]); acc[2][3] = fmaf(a2, b.w, acc[2][3]);
        acc[3][0] = fmaf(a3, b.x, acc[3][0]); acc[3][1] = fmaf(a3, b.y, acc[3][1]);
        acc[3][2] = fmaf(a3, b.z, acc[3][2]); acc[3][3] = fmaf(a3, b.w, acc[3][3]);
    }

    const int plane = col / PLANEW;
    const int c = col % PLANEW;
    __half* base = Hs + (size_t)plane * ((size_t)n * PLANEW) + c;
#pragma unroll
    for (int rr = 0; rr < 4; ++rr) {
        int node = node0 + r0 + rr;
        if (node < n) {
            float di = dinv[node];
            uint2 pk;
            pk.x = pack2h(acc[rr][0] * di, acc[rr][1] * di);
            pk.y = pack2h(acc[rr][2] * di, acc[rr][3] * di);
            *(uint2*)(base + (size_t)node * PLANEW) = pk;
        }
    }
}

__device__ inline void add8h(float* acc, uint4 p) {
    unsigned int w[4] = {p.x, p.y, p.z, p.w};
#pragma unroll
    for (int t = 0; t < 4; ++t) {
        __half2 h = *(const __half2*)&w[t];
        float2 f = __half22float2(h);
        acc[2 * t] += f.x;
        acc[2 * t + 1] += f.y;
    }
}

// Pull aggregation + norm + bias + tanh for ONE plane of PLANEW fp16 cols.
// HsP: plane base (row stride PLANEW). Bp: bias slice. OUTp: output base
// pre-offset to this plane's columns, row stride OUTSTRIDE (f32).
template <int PLANEW, int OUTSTRIDE>
__global__ __launch_bounds__(256) void pull_plane(
    const int* __restrict__ row_start, const int* __restrict__ deg,
    const int* __restrict__ col, const __half* __restrict__ HsP,
    const float* __restrict__ dinv, const float* __restrict__ Bp,
    float* __restrict__ OUTp, int n) {
    constexpr int TPE = PLANEW / 8;
    long long gid = (long long)blockIdx.x * 256 + threadIdx.x;
    int node = (int)(gid / TPE);
    int lane = (int)(gid % TPE);
    if (node >= n) return;
    const int beg = row_start[node];
    const int cnt = deg[node];
    const size_t lo = (size_t)lane * 8;

    float acc[8] = {0.f, 0.f, 0.f, 0.f, 0.f, 0.f, 0.f, 0.f};
    add8h(acc, *(const uint4*)(HsP + (size_t)node * PLANEW + lo));  // self term

    int j = 0;
    for (; j + 4 <= cnt; j += 4) {
        int s0 = col[beg + j + 0], s1 = col[beg + j + 1];
        int s2 = col[beg + j + 2], s3 = col[beg + j + 3];
        uint4 p0 = *(const uint4*)(HsP + (size_t)s0 * PLANEW + lo);
        uint4 p1 = *(const uint4*)(HsP + (size_t)s1 * PLANEW + lo);
        uint4 p2 = *(const uint4*)(HsP + (size_t)s2 * PLANEW + lo);
        uint4 p3 = *(const uint4*)(HsP + (size_t)s3 * PLANEW + lo);
        add8h(acc, p0); add8h(acc, p1); add8h(acc, p2); add8h(acc, p3);
    }
    for (; j < cnt; ++j) {
        int s = col[beg + j];
        add8h(acc, *(const uint4*)(HsP + (size_t)s * PLANEW + lo));
    }

    float di = dinv[node];
    float4 b0 = *(const float4*)(Bp + lo);
    float4 b1 = *(const float4*)(Bp + lo + 4);
    float4 r0, r1;
    r0.x = tanhf(fmaf(acc[0], di, b0.x));
    r0.y = tanhf(fmaf(acc[1], di, b0.y));
    r0.z = tanhf(fmaf(acc[2], di, b0.z));
    r0.w = tanhf(fmaf(acc[3], di, b0.w));
    r1.x = tanhf(fmaf(acc[4], di, b1.x));
    r1.y = tanhf(fmaf(acc[5], di, b1.y));
    r1.z = tanhf(fmaf(acc[6], di, b1.z));
    r1.w = tanhf(fmaf(acc[7], di, b1.w));
    float* op = OUTp + (size_t)node * OUTSTRIDE + lo;
    *(float4*)(op) = r0;
    *(float4*)(op + 4) = r1;
}

__global__ void classifier_kernel(const float* __restrict__ Hf,
                                  const float* __restrict__ Wc,
                                  const float* __restrict__ bc,
                                  float* __restrict__ out, int n) {
    int v = blockIdx.x * blockDim.x + threadIdx.x;
    if (v >= n) return;
    float o0 = bc[0], o1 = bc[1];
    const float* h = Hf + (size_t)v * 16;
#pragma unroll
    for (int k = 0; k < 16; ++k) {
        float hv = h[k];
        o0 = fmaf(hv, Wc[k * 2 + 0], o0);
        o1 = fmaf(hv, Wc[k * 2 + 1], o1);
    }
    out[(size_t)v * 2 + 0] = o0;
    out[(size_t)v * 2 + 1] = o1;
}

extern "C" void kernel_launch(void* const* d_in, const int* in_sizes, int n_in,
                              void* d_out, int out_size, void* d_ws, size_t ws_size,
                              hipStream_t stream) {
    const float* x  = (const float*)d_in[0];
    const int* ei   = (const int*)d_in[1];   // int32 (harness converts)
    const float* W1 = (const float*)d_in[2];
    const float* b1 = (const float*)d_in[3];
    const float* W2 = (const float*)d_in[4];
    const float* b2 = (const float*)d_in[5];
    const float* W3 = (const float*)d_in[6];
    const float* b3 = (const float*)d_in[7];
    const float* Wc = (const float*)d_in[8];
    const float* bc = (const float*)d_in[9];

    const int n = in_sizes[0] / 256;
    const int E = in_sizes[1] / 2;
    const int nbuc = (n + 255) >> BSHIFT;          // 391
    const int nch  = (E + EPB - 1) / EPB;          // 196
    const int NH   = nbuc * nch;                   // 76,636
    const int nb2  = (NH + 255) / 256;             // 300 <= 512

    float* outp = (float*)d_out;             // [n,2]
    float* outh = outp + (size_t)n * 2;      // [n,16]

    int*    deg       = (int*)d_ws;
    float*  dinv      = (float*)d_ws + (size_t)n;
    int*    row_start = (int*)d_ws + 2 * (size_t)n;
    int*    histG     = (int*)d_ws + 3 * (size_t)n;
    int*    incl      = histG + NH;
    int*    bsum      = incl + NH;
    int*    offs      = bsum + 512;
    int*    col       = offs + NH;
    __half* HsH       = (__half*)(col + E);
    float*  xbuf      = (float*)(HsH + (size_t)n * 128);
    uint2*  ebuf      = (uint2*)xbuf;        // alias: dead before pull1 writes xbuf

    const size_t PS = (size_t)n * 32;        // plane stride (half elements)

    // --- atomic-free CSR build (shared by all 3 layers) ---
    hist_bucket<<<nch, 256, 0, stream>>>(ei, E, nbuc, nch, histG);
    scan_block<<<nb2, 256, 0, stream>>>(histG, NH, incl, bsum);
    scan_sums<<<1, 512, 0, stream>>>(bsum, nb2);
    finalize_scan<<<nb2, 256, 0, stream>>>(incl, bsum, histG, NH, offs);
    bucket_scatter<<<nch, 256, 0, stream>>>(ei, E, nbuc, nch, offs, ebuf);
    bucket_build<<<nbuc, 256, 0, stream>>>(ebuf, offs, E, nbuc, nch, n,
                                           col, deg, row_start, dinv);

    const int pblk32 = (int)(((long long)n * 4 + 255) / 256);  // PLANEW=32 grids

    // --- layer 1: 256 -> 128 (4 planes of 32) ---
    gemm_tile_p<256, 128, 32, 32><<<(n + 31) / 32, 256, 0, stream>>>(x, W1, dinv, HsH, n);
    for (int p = 0; p < 4; ++p)
        pull_plane<32, 128><<<pblk32, 256, 0, stream>>>(
            row_start, deg, col, HsH + (size_t)p * PS, dinv, b1 + p * 32,
            xbuf + p * 32, n);

    // --- layer 2: 128 -> 64 (2 planes of 32) ---
    gemm_tile_p<128, 64, 64, 32><<<(n + 63) / 64, 256, 0, stream>>>(xbuf, W2, dinv, HsH, n);
    for (int p = 0; p < 2; ++p)
        pull_plane<32, 64><<<pblk32, 256, 0, stream>>>(
            row_start, deg, col, HsH + (size_t)p * PS, dinv, b2 + p * 32,
            xbuf + p * 32, n);

    // --- layer 3: 64 -> 16 (single 16-wide plane, 3.2 MB: already L2-sized) ---
    gemm_tile_p<64, 16, 256, 16><<<(n + 255) / 256, 256, 0, stream>>>(xbuf, W3, dinv, HsH, n);
    pull_plane<16, 16><<<(int)(((long long)n * 2 + 255) / 256), 256, 0, stream>>>(
        row_start, deg, col, HsH, dinv, b3, outh, n);

    // --- classifier head ---
    classifier_kernel<<<(n + 255) / 256, 256, 0, stream>>>(outh, Wc, bc, outp, n);
}

// Round 9
// 718.380 us; speedup vs baseline: 1.1730x; 1.1730x over previous
//
#include <hip/hip_runtime.h>
#include <hip/hip_fp16.h>
#include <cstdint>
#include <cstddef>

// ---------------------------------------------------------------------------
// GCNClassifier: 3x (GCNConv + tanh) + linear head, N=100k nodes, E=3.2M edges
// Round 9: revert round-8 plane split (regressed: hit-rate gain < 4x col
// re-read + tail costs). Back to monolithic fp16 Hs pulls. New:
//  - gemm inner loop k-step 4 w/ ds_read_b128: 4 LDS insts + 64 FMA per step
//    (was 16 LDS insts) -- round-8 profile showed gemm VALUBusy 49%, occ 38%,
//    issue-bound at 28% of f32 peak.
//  - pull loop unrolled 8-deep (8 gathers in flight per lane).
//   Hs[v]  = fp16( (X@W)[v] * dinv[v] )               (gemm epilogue)
//   out[v] = tanh( dinv[v]*(Hs[v] + sum_{u->v} Hs[u]) + b )   (pull, fused)
// CSR built atomic-free (bucketed counting sort, round 7). edge_index int32.
// ---------------------------------------------------------------------------

#define EPB 16384        // edges per hist/scatter chunk
#define BSHIFT 8         // bucket = dst >> 8 (256 dst nodes per bucket)
#define NBUC_MAX 512     // 100000>>8 = 390 max bucket id
#define BCAP 12800       // bucket_build LDS edge capacity (avg 8192, 50+ sigma)

// --- generic two-level exclusive scan ---
__global__ __launch_bounds__(256) void scan_block(const int* __restrict__ src, int n,
                                                  int* __restrict__ incl,
                                                  int* __restrict__ bsum) {
    int tid = threadIdx.x;
    int v = blockIdx.x * 256 + tid;
    int val = (v < n) ? src[v] : 0;
    int lane = tid & 63, w = tid >> 6;
#pragma unroll
    for (int off = 1; off < 64; off <<= 1) {
        int t = __shfl_up(val, off, 64);
        if (lane >= off) val += t;
    }
    __shared__ int wsum[4];
    if (lane == 63) wsum[w] = val;
    __syncthreads();
#pragma unroll
    for (int i = 0; i < 4; ++i)
        if (i < w) val += wsum[i];
    if (v < n) incl[v] = val;
    if (tid == 255) bsum[blockIdx.x] = val;
}

__global__ __launch_bounds__(512) void scan_sums(int* __restrict__ bsum, int nb) {
    int tid = threadIdx.x;              // nb <= 512
    int val = (tid < nb) ? bsum[tid] : 0;
    int lane = tid & 63, w = tid >> 6;
#pragma unroll
    for (int off = 1; off < 64; off <<= 1) {
        int t = __shfl_up(val, off, 64);
        if (lane >= off) val += t;
    }
    __shared__ int wsum[8];
    if (lane == 63) wsum[w] = val;
    __syncthreads();
#pragma unroll
    for (int i = 0; i < 8; ++i)
        if (i < w) val += wsum[i];
    if (tid < nb) bsum[tid] = val;
}

__global__ __launch_bounds__(256) void finalize_scan(
    const int* __restrict__ incl, const int* __restrict__ bsum,
    const int* __restrict__ src, int n, int* __restrict__ excl) {
    int v = blockIdx.x * 256 + threadIdx.x;
    if (v >= n) return;
    int boff = (blockIdx.x == 0) ? 0 : bsum[blockIdx.x - 1];
    excl[v] = boff + incl[v] - src[v];
}

// Pass A: per-chunk histogram over dst buckets (LDS atomics only).
__global__ __launch_bounds__(256) void hist_bucket(
    const int* __restrict__ ei, int E, int nbuc, int nch,
    int* __restrict__ histG) {
    __shared__ int h[NBUC_MAX];
    const int k = blockIdx.x;
    for (int b = threadIdx.x; b < NBUC_MAX; b += 256) h[b] = 0;
    __syncthreads();
    const int base = k * EPB, end = min(E, base + EPB);
    for (int i = base + threadIdx.x; i < end; i += 256)
        atomicAdd(&h[ei[(size_t)E + i] >> BSHIFT], 1);
    __syncthreads();
    for (int b = threadIdx.x; b < nbuc; b += 256)
        histG[(size_t)b * nch + k] = h[b];
}

// Pass C: scatter (src,dst) pairs into per-(bucket,chunk) contiguous regions.
__global__ __launch_bounds__(256) void bucket_scatter(
    const int* __restrict__ ei, int E, int nbuc, int nch,
    const int* __restrict__ offs, uint2* __restrict__ ebuf) {
    __shared__ int cur[NBUC_MAX];
    const int k = blockIdx.x;
    for (int b = threadIdx.x; b < nbuc; b += 256)
        cur[b] = offs[(size_t)b * nch + k];
    __syncthreads();
    const int base = k * EPB, end = min(E, base + EPB);
    for (int i = base + threadIdx.x; i < end; i += 256) {
        int s = ei[i];
        int d = ei[(size_t)E + i];
        int pos = atomicAdd(&cur[d >> BSHIFT], 1);
        ebuf[pos] = make_uint2((unsigned)s, (unsigned)d);
    }
}

// Pass D: one block per bucket -> exact CSR slice + deg/row_start/dinv.
__global__ __launch_bounds__(256) void bucket_build(
    const uint2* __restrict__ ebuf, const int* __restrict__ offs,
    int E, int nbuc, int nch, int n,
    int* __restrict__ col, int* __restrict__ deg,
    int* __restrict__ row_start, float* __restrict__ dinv) {
    const int b = blockIdx.x;
    const int tid = threadIdx.x;
    const int estart = offs[(size_t)b * nch];
    const int eend = (b + 1 < nbuc) ? offs[(size_t)(b + 1) * nch] : E;
    const int cnt = eend - estart;

    __shared__ int degl[256];
    __shared__ int curl[256];
    __shared__ int wsum[4];
    __shared__ int colstage[BCAP];

    degl[tid] = 0;
    __syncthreads();
    for (int i = tid; i < cnt; i += 256)
        atomicAdd(&degl[ebuf[estart + i].y & 255], 1);
    __syncthreads();
    int myDeg = degl[tid];
    int val = myDeg;
    int lane = tid & 63, w = tid >> 6;
#pragma unroll
    for (int off = 1; off < 64; off <<= 1) {
        int t = __shfl_up(val, off, 64);
        if (lane >= off) val += t;
    }
    if (lane == 63) wsum[w] = val;
    __syncthreads();
#pragma unroll
    for (int i = 0; i < 4; ++i)
        if (i < w) val += wsum[i];
    int excl = val - myDeg;
    curl[tid] = excl;
    int v = (b << BSHIFT) + tid;
    if (v < n) {
        deg[v] = myDeg;
        row_start[v] = estart + excl;
        dinv[v] = rsqrtf((float)(myDeg + 1));   // +1 self loop
    }
    __syncthreads();
    if (cnt <= BCAP) {
        for (int i = tid; i < cnt; i += 256) {
            uint2 e = ebuf[estart + i];
            int pos = atomicAdd(&curl[e.y & 255], 1);
            colstage[pos] = (int)e.x;
        }
        __syncthreads();
        for (int i = tid; i < cnt; i += 256)
            col[estart + i] = colstage[i];
    } else {  // safety fallback
        for (int i = tid; i < cnt; i += 256) {
            uint2 e = ebuf[estart + i];
            int pos = atomicAdd(&curl[e.y & 255], 1);
            col[estart + pos] = (int)e.x;
        }
    }
}

__device__ inline unsigned int pack2h(float a, float b) {
    __half ha = __float2half_rn(a), hb = __float2half_rn(b);
    unsigned short ua = *(unsigned short*)&ha, ub = *(unsigned short*)&hb;
    return (unsigned int)ua | ((unsigned int)ub << 16);
}

// Register-tiled GEMM: Hs = fp16( (X @ W) * dinv[row] ). 4x4 acc per thread.
// Inner loop k-step 4: 4 ds_read_b128 (half-wave broadcast) + 4 W float4 (L1)
// + 64 FMA -> 4x fewer LDS issues per FMA than the round-4..8 version.
template <int FIN, int FOUT, int TM>
__global__ __launch_bounds__(256) void gemm_tile_h(
    const float* __restrict__ X, const float* __restrict__ W,
    const float* __restrict__ dinv, __half* __restrict__ Hs, int n) {
    constexpr int CT = FOUT / 4;
    constexpr int RG = 256 / CT;
    static_assert(TM == RG * 4, "tile mismatch");
    constexpr int LROW = FIN + 4;   // rows stay 16-B aligned (FIN,4 mult of 4)
    __shared__ float xs[TM][LROW];

    const int node0 = blockIdx.x * TM;
    const int tid = threadIdx.x;

    constexpr int C4 = FIN / 4;
    for (int i = tid; i < TM * C4; i += 256) {
        int r = i / C4, c = i % C4;
        float4 v = make_float4(0.f, 0.f, 0.f, 0.f);
        if (node0 + r < n) v = *(const float4*)(X + (size_t)(node0 + r) * FIN + c * 4);
        *(float4*)&xs[r][c * 4] = v;
    }
    __syncthreads();

    const int col = (tid % CT) * 4;
    const int r0 = (tid / CT) * 4;

    float acc[4][4];
#pragma unroll
    for (int i = 0; i < 4; ++i)
#pragma unroll
        for (int j = 0; j < 4; ++j) acc[i][j] = 0.f;

#pragma unroll 2
    for (int k = 0; k < FIN; k += 4) {
        float4 w0 = *(const float4*)(W + (size_t)(k + 0) * FOUT + col);
        float4 w1 = *(const float4*)(W + (size_t)(k + 1) * FOUT + col);
        float4 w2 = *(const float4*)(W + (size_t)(k + 2) * FOUT + col);
        float4 w3 = *(const float4*)(W + (size_t)(k + 3) * FOUT + col);
        float4 av[4];
        av[0] = *(const float4*)&xs[r0 + 0][k];
        av[1] = *(const float4*)&xs[r0 + 1][k];
        av[2] = *(const float4*)&xs[r0 + 2][k];
        av[3] = *(const float4*)&xs[r0 + 3][k];
#pragma unroll
        for (int rr = 0; rr < 4; ++rr) {
            acc[rr][0] = fmaf(av[rr].x, w0.x, acc[rr][0]);
            acc[rr][1] = fmaf(av[rr].x, w0.y, acc[rr][1]);
            acc[rr][2] = fmaf(av[rr].x, w0.z, acc[rr][2]);
            acc[rr][3] = fmaf(av[rr].x, w0.w, acc[rr][3]);
            acc[rr][0] = fmaf(av[rr].y, w1.x, acc[rr][0]);
            acc[rr][1] = fmaf(av[rr].y, w1.y, acc[rr][1]);
            acc[rr][2] = fmaf(av[rr].y, w1.z, acc[rr][2]);
            acc[rr][3] = fmaf(av[rr].y, w1.w, acc[rr][3]);
            acc[rr][0] = fmaf(av[rr].z, w2.x, acc[rr][0]);
            acc[rr][1] = fmaf(av[rr].z, w2.y, acc[rr][1]);
            acc[rr][2] = fmaf(av[rr].z, w2.z, acc[rr][2]);
            acc[rr][3] = fmaf(av[rr].z, w2.w, acc[rr][3]);
            acc[rr][0] = fmaf(av[rr].w, w3.x, acc[rr][0]);
            acc[rr][1] = fmaf(av[rr].w, w3.y, acc[rr][1]);
            acc[rr][2] = fmaf(av[rr].w, w3.z, acc[rr][2]);
            acc[rr][3] = fmaf(av[rr].w, w3.w, acc[rr][3]);
        }
    }

#pragma unroll
    for (int rr = 0; rr < 4; ++rr) {
        int node = node0 + r0 + rr;
        if (node < n) {
            float di = dinv[node];
            uint2 pk;
            pk.x = pack2h(acc[rr][0] * di, acc[rr][1] * di);
            pk.y = pack2h(acc[rr][2] * di, acc[rr][3] * di);
            *(uint2*)(Hs + (size_t)node * FOUT + col) = pk;
        }
    }
}

__device__ inline void add8h(float* acc, uint4 p) {
    unsigned int w[4] = {p.x, p.y, p.z, p.w};
#pragma unroll
    for (int t = 0; t < 4; ++t) {
        __half2 h = *(const __half2*)&w[t];
        float2 f = __half22float2(h);
        acc[2 * t] += f.x;
        acc[2 * t + 1] += f.y;
    }
}

// Pull aggregation + norm + bias + tanh from fp16 Hs. F/8 lanes per dst node,
// 8 neighbor rows in flight per lane (MLP depth 8).
template <int F>
__global__ __launch_bounds__(256) void pull_agg_h(
    const int* __restrict__ row_start, const int* __restrict__ deg,
    const int* __restrict__ col, const __half* __restrict__ Hs,
    const float* __restrict__ dinv, const float* __restrict__ B,
    float* __restrict__ OUT, int n) {
    constexpr int TPE = F / 8;
    long long gid = (long long)blockIdx.x * 256 + threadIdx.x;
    int node = (int)(gid / TPE);
    int lane = (int)(gid % TPE);
    if (node >= n) return;
    const int beg = row_start[node];
    const int cnt = deg[node];
    const size_t lo = (size_t)lane * 8;

    float acc[8] = {0.f, 0.f, 0.f, 0.f, 0.f, 0.f, 0.f, 0.f};
    add8h(acc, *(const uint4*)(Hs + (size_t)node * F + lo));  // self term

    int j = 0;
    for (; j + 8 <= cnt; j += 8) {
        int s0 = col[beg + j + 0], s1 = col[beg + j + 1];
        int s2 = col[beg + j + 2], s3 = col[beg + j + 3];
        int s4 = col[beg + j + 4], s5 = col[beg + j + 5];
        int s6 = col[beg + j + 6], s7 = col[beg + j + 7];
        uint4 p0 = *(const uint4*)(Hs + (size_t)s0 * F + lo);
        uint4 p1 = *(const uint4*)(Hs + (size_t)s1 * F + lo);
        uint4 p2 = *(const uint4*)(Hs + (size_t)s2 * F + lo);
        uint4 p3 = *(const uint4*)(Hs + (size_t)s3 * F + lo);
        uint4 p4 = *(const uint4*)(Hs + (size_t)s4 * F + lo);
        uint4 p5 = *(const uint4*)(Hs + (size_t)s5 * F + lo);
        uint4 p6 = *(const uint4*)(Hs + (size_t)s6 * F + lo);
        uint4 p7 = *(const uint4*)(Hs + (size_t)s7 * F + lo);
        add8h(acc, p0); add8h(acc, p1); add8h(acc, p2); add8h(acc, p3);
        add8h(acc, p4); add8h(acc, p5); add8h(acc, p6); add8h(acc, p7);
    }
    for (; j < cnt; ++j) {
        int s = col[beg + j];
        add8h(acc, *(const uint4*)(Hs + (size_t)s * F + lo));
    }

    float di = dinv[node];
    float4 b0 = *(const float4*)(B + lo);
    float4 b1 = *(const float4*)(B + lo + 4);
    float4 r0, r1;
    r0.x = tanhf(fmaf(acc[0], di, b0.x));
    r0.y = tanhf(fmaf(acc[1], di, b0.y));
    r0.z = tanhf(fmaf(acc[2], di, b0.z));
    r0.w = tanhf(fmaf(acc[3], di, b0.w));
    r1.x = tanhf(fmaf(acc[4], di, b1.x));
    r1.y = tanhf(fmaf(acc[5], di, b1.y));
    r1.z = tanhf(fmaf(acc[6], di, b1.z));
    r1.w = tanhf(fmaf(acc[7], di, b1.w));
    float* op = OUT + (size_t)node * F + lo;
    *(float4*)(op) = r0;
    *(float4*)(op + 4) = r1;
}

__global__ void classifier_kernel(const float* __restrict__ Hf,
                                  const float* __restrict__ Wc,
                                  const float* __restrict__ bc,
                                  float* __restrict__ out, int n) {
    int v = blockIdx.x * blockDim.x + threadIdx.x;
    if (v >= n) return;
    float o0 = bc[0], o1 = bc[1];
    const float* h = Hf + (size_t)v * 16;
#pragma unroll
    for (int k = 0; k < 16; ++k) {
        float hv = h[k];
        o0 = fmaf(hv, Wc[k * 2 + 0], o0);
        o1 = fmaf(hv, Wc[k * 2 + 1], o1);
    }
    out[(size_t)v * 2 + 0] = o0;
    out[(size_t)v * 2 + 1] = o1;
}

extern "C" void kernel_launch(void* const* d_in, const int* in_sizes, int n_in,
                              void* d_out, int out_size, void* d_ws, size_t ws_size,
                              hipStream_t stream) {
    const float* x  = (const float*)d_in[0];
    const int* ei   = (const int*)d_in[1];   // int32 (harness converts)
    const float* W1 = (const float*)d_in[2];
    const float* b1 = (const float*)d_in[3];
    const float* W2 = (const float*)d_in[4];
    const float* b2 = (const float*)d_in[5];
    const float* W3 = (const float*)d_in[6];
    const float* b3 = (const float*)d_in[7];
    const float* Wc = (const float*)d_in[8];
    const float* bc = (const float*)d_in[9];

    const int n = in_sizes[0] / 256;
    const int E = in_sizes[1] / 2;
    const int nbuc = (n + 255) >> BSHIFT;          // 391
    const int nch  = (E + EPB - 1) / EPB;          // 196
    const int NH   = nbuc * nch;                   // 76,636
    const int nb2  = (NH + 255) / 256;             // 300 <= 512

    float* outp = (float*)d_out;             // [n,2]
    float* outh = outp + (size_t)n * 2;      // [n,16]

    int*    deg       = (int*)d_ws;
    float*  dinv      = (float*)d_ws + (size_t)n;
    int*    row_start = (int*)d_ws + 2 * (size_t)n;
    int*    histG     = (int*)d_ws + 3 * (size_t)n;
    int*    incl      = histG + NH;
    int*    bsum      = incl + NH;
    int*    offs      = bsum + 512;
    int*    col       = offs + NH;
    __half* HsH       = (__half*)(col + E);
    float*  xbuf      = (float*)(HsH + (size_t)n * 128);
    uint2*  ebuf      = (uint2*)xbuf;        // alias: dead before pull1 writes xbuf

    // --- atomic-free CSR build (shared by all 3 layers) ---
    hist_bucket<<<nch, 256, 0, stream>>>(ei, E, nbuc, nch, histG);
    scan_block<<<nb2, 256, 0, stream>>>(histG, NH, incl, bsum);
    scan_sums<<<1, 512, 0, stream>>>(bsum, nb2);
    finalize_scan<<<nb2, 256, 0, stream>>>(incl, bsum, histG, NH, offs);
    bucket_scatter<<<nch, 256, 0, stream>>>(ei, E, nbuc, nch, offs, ebuf);
    bucket_build<<<nbuc, 256, 0, stream>>>(ebuf, offs, E, nbuc, nch, n,
                                           col, deg, row_start, dinv);

    // --- layer 1: 256 -> 128 ---
    gemm_tile_h<256, 128, 32><<<(n + 31) / 32, 256, 0, stream>>>(x, W1, dinv, HsH, n);
    pull_agg_h<128><<<(int)(((long long)n * 16 + 255) / 256), 256, 0, stream>>>(
        row_start, deg, col, HsH, dinv, b1, xbuf, n);

    // --- layer 2: 128 -> 64 ---
    gemm_tile_h<128, 64, 64><<<(n + 63) / 64, 256, 0, stream>>>(xbuf, W2, dinv, HsH, n);
    pull_agg_h<64><<<(int)(((long long)n * 8 + 255) / 256), 256, 0, stream>>>(
        row_start, deg, col, HsH, dinv, b2, xbuf, n);

    // --- layer 3: 64 -> 16 ---
    gemm_tile_h<64, 16, 256><<<(n + 255) / 256, 256, 0, stream>>>(xbuf, W3, dinv, HsH, n);
    pull_agg_h<16><<<(int)(((long long)n * 2 + 255) / 256), 256, 0, stream>>>(
        row_start, deg, col, HsH, dinv, b3, outh, n);

    // --- classifier head ---
    classifier_kernel<<<(n + 255) / 256, 256, 0, stream>>>(outh, Wc, bc, outp, n);
}